// Round 20
// baseline (370.027 us; speedup 1.0000x reference)
//
#include <hip/hip_runtime.h>
#include <hip/hip_bf16.h>

#define Nn 100000
#define Ee 1600000
#define Ff 128
#define Hh 128
#define Cc 10
#define Gg 512

#define NBK 391                         // ceil(Nn/256) buckets of 256 dst
#define ABLK 4096                       // edges per bin_edges block
#define NABLK ((Ee + ABLK - 1) / ABLK)  // 391
#define BMAX 6656                       // padded bucket capacity

#define CAST_BLKS ((Nn * Ff / 4 + 255) / 256)        // 3125
#define PACK_BLKS ((9 * 16384 + 255) / 256)          // 576
#define GS_BLKS   ((Nn + 1 + 255) / 256)             // 391

typedef short bf16x8 __attribute__((ext_vector_type(8)));
typedef float f32x4 __attribute__((ext_vector_type(4)));
typedef float f32x2 __attribute__((ext_vector_type(2)));

__device__ __forceinline__ unsigned short f2bf(float f) {
    unsigned u = __float_as_uint(f);
    u += 0x7fffu + ((u >> 16) & 1u);
    return (unsigned short)(u >> 16);
}
__device__ __forceinline__ unsigned pk2(float a, float b) {
    return (unsigned)f2bf(a) | ((unsigned)f2bf(b) << 16);
}

// ---- merged prep: cast_x | pack_w | graph_starts, partitioned by blockIdx ----
__global__ __launch_bounds__(256) void prep(const float* __restrict__ x,
                                            uint2* __restrict__ xb,
                                            const float* __restrict__ W1, const float* __restrict__ r1,
                                            const float* __restrict__ W2, const float* __restrict__ r2,
                                            const float* __restrict__ W3, const float* __restrict__ r3,
                                            unsigned short* __restrict__ wp,
                                            const int* __restrict__ batch,
                                            int* __restrict__ gstart) {
    int b = blockIdx.x;
    if (b < CAST_BLKS) {
        int i = b * 256 + threadIdx.x;
        if (i >= Nn * Ff / 4) return;
        float4 v = ((const float4*)x)[i];
        uint2 o;
        o.x = pk2(v.x, v.y);
        o.y = pk2(v.z, v.w);
        xb[i] = o;
    } else if (b < CAST_BLKS + PACK_BLKS) {
        int t = (b - CAST_BLKS) * 256 + threadIdx.x;
        if (t >= 9 * 16384) return;
        int i = t & 7, l = (t >> 3) & 63, s = (t >> 9) & 3, c = (t >> 11) & 7, m = t >> 14;
        int k = s * 32 + ((l >> 4) << 3) + i;
        int n = (c << 4) + (l & 15);
        int q = m / 3, j = m % 3;
        const float* Ws[3] = {W1, W2, W3};
        const float* rs[3] = {r1, r2, r3};
        const float* src = (j == 0) ? rs[q] : (Ws[q] + (size_t)(j - 1) * Ff * Hh);
        wp[t] = f2bf(src[k * Hh + n]);
    } else {
        int n = (b - CAST_BLKS - PACK_BLKS) * 256 + threadIdx.x;
        if (n > Nn) return;
        int bp = (n == 0) ? -1 : batch[n - 1];
        int bc = (n == Nn) ? Gg : batch[n];
        for (int g = bp + 1; g <= bc; ++g) gstart[g] = n;
    }
}

// ---- CSR build, pass 1: LDS-staged binning by dst>>8 into padded buckets ----
__global__ __launch_bounds__(512) void bin_edges(const int* __restrict__ ei,
                                                 const int* __restrict__ ea,
                                                 int* __restrict__ bucketCur,
                                                 int* __restrict__ csr) {
    __shared__ int lcnt[512];
    __shared__ int lstart[512];
    __shared__ int gbase[512];
    __shared__ int lcur[512];
    __shared__ int stage[ABLK];
    __shared__ unsigned short sbkt[ABLK];
    int t = threadIdx.x;
    int base = blockIdx.x * ABLK;
    int nhere = min(ABLK, Ee - base);
    lcnt[t] = 0;
    __syncthreads();
    for (int j = t; j < nhere; j += 512)
        atomicAdd(&lcnt[ei[Ee + base + j] >> 8], 1);
    __syncthreads();
    int v = lcnt[t];
    if (t < NBK) gbase[t] = (v > 0) ? atomicAdd(&bucketCur[t], v) : 0;
    int* pa = lcnt; int* pb = lstart;
    for (int off = 1; off < 512; off <<= 1) {
        int x = pa[t] + ((t >= off) ? pa[t - off] : 0);
        __syncthreads();
        pb[t] = x;
        __syncthreads();
        int* tmp = pa; pa = pb; pb = tmp;
    }
    int excl = pa[t] - v;
    __syncthreads();
    lstart[t] = excl;
    lcur[t] = excl;
    __syncthreads();
    for (int j = t; j < nhere; j += 512) {
        int e = base + j;
        int d = ei[Ee + e];
        int srcv = ei[e];
        int r = ea[e] & 1;
        int bkt = d >> 8;
        int lp = atomicAdd(&lcur[bkt], 1);
        stage[lp] = (srcv << 9) | ((d & 255) << 1) | r;
        sbkt[lp] = (unsigned short)bkt;
    }
    __syncthreads();
    for (int j = t; j < nhere; j += 512) {
        int bkt = sbkt[j];
        csr[(size_t)bkt * BMAX + gbase[bkt] + (j - lstart[bkt])] = stage[j];
    }
}

// ---- CSR build, pass 2: per-bucket counting sort by (dstLow, rel).
//      Both relation segments padded to Lp = 4*ceil(max(n0,n1)/4), sentinel
//      src = Nn (zero row). Emits rowstart/mid + packed counts. ----
__global__ __launch_bounds__(512) void sort_bucket(const int* __restrict__ bucketCur,
                                                   int* __restrict__ csr,
                                                   int* __restrict__ rowstart,
                                                   int* __restrict__ mid,
                                                   int* __restrict__ cnts) {
    __shared__ int cnt_[512];
    __shared__ int sa_[512];
    __shared__ int sb_[512];
    __shared__ int cur_[512];
    __shared__ int stage[BMAX];
    __shared__ int npad_s;
    int b = blockIdx.x;
    int t = threadIdx.x;
    int s = b * BMAX;
    int n = bucketCur[b];
    cnt_[t] = 0;
    __syncthreads();
    for (int j = t; j < n; j += 512)
        atomicAdd(&cnt_[csr[(size_t)s + j] & 511], 1);
    __syncthreads();
    int c_self = cnt_[t];
    int c_pair = cnt_[t ^ 1];
    int Lp = (max(c_self, c_pair) + 3) & ~3;
    int v = Lp;
    sa_[t] = v;
    __syncthreads();
    int* pa = sa_; int* pb = sb_;
    for (int off = 1; off < 512; off <<= 1) {
        int x = pa[t] + ((t >= off) ? pa[t - off] : 0);
        __syncthreads();
        pb[t] = x;
        __syncthreads();
        int* tmp = pa; pa = pb; pb = tmp;
    }
    int excl = pa[t] - v;
    if (t == 511) npad_s = excl + v;
    __syncthreads();
    sa_[t] = excl;
    cur_[t] = excl;
    __syncthreads();
    int npad = npad_s;
    if (t < 256) {
        int d = b * 256 + t;
        if (d < Nn) {
            rowstart[d] = s + sa_[2 * t];
            mid[d]      = s + sa_[2 * t + 1];
            cnts[d]     = cnt_[2 * t] | (cnt_[2 * t + 1] << 16);
        }
    }
    for (int j = t; j < npad; j += 512) stage[j] = Nn;
    __syncthreads();
    for (int j = t; j < n; j += 512) {
        int rec = csr[(size_t)s + j];
        int lp = atomicAdd(&cur_[rec & 511], 1);
        stage[lp] = rec >> 9;          // src index
    }
    __syncthreads();
    for (int j = t; j < npad; j += 512)
        csr[(size_t)s + j] = stage[j];
}

// ---- aggregation: 16 lanes per dst, 4 dsts per wave. Each lane privately
//      accumulates its 8 columns over all edges of its group's dst — no
//      cross-lane reduce, full-width stores, prologue amortized 4x.
//      Per-dst padded csr segments make all reads valid (sentinel = zero row). ----
__device__ __forceinline__ void accbf(f32x2 A[4], uint4 v) {
    A[0] += (f32x2){__uint_as_float(v.x << 16), __uint_as_float(v.x & 0xffff0000u)};
    A[1] += (f32x2){__uint_as_float(v.y << 16), __uint_as_float(v.y & 0xffff0000u)};
    A[2] += (f32x2){__uint_as_float(v.z << 16), __uint_as_float(v.z & 0xffff0000u)};
    A[3] += (f32x2){__uint_as_float(v.w << 16), __uint_as_float(v.w & 0xffff0000u)};
}

__global__ __launch_bounds__(256) void aggregate(const unsigned short* __restrict__ xb,
                                                 const int* __restrict__ csr,
                                                 const int* __restrict__ rowstart,
                                                 const int* __restrict__ mid,
                                                 const int* __restrict__ cnts,
                                                 unsigned int* __restrict__ xg0,
                                                 unsigned int* __restrict__ xg1) {
    int t = threadIdx.x;
    int lane = t & 63;
    int grp = lane >> 4;            // 4 dst-groups per wave
    int gl = lane & 15;             // lane within group: owns 8 columns
    int d = blockIdx.x * 16 + (t >> 6) * 4 + grp;
    if (d >= Nn) return;
    int c8 = gl * 8;
    int s = rowstart[d], md = mid[d];
    int cn = cnts[d];
    int n0 = cn & 0xffff, n1 = cn >> 16;
    int mx = max(n0, n1);           // <= padded segment length Lp

    f32x2 A0[4], A1[4];
    #pragma unroll
    for (int j = 0; j < 4; ++j) { A0[j] = (f32x2){0.f, 0.f}; A1[j] = (f32x2){0.f, 0.f}; }

    for (int it = 0; it < mx; ++it) {
        int r0 = csr[s + it];
        int r1 = csr[md + it];
        uint4 v0 = *(const uint4*)(xb + (size_t)r0 * Hh + c8);
        uint4 v1 = *(const uint4*)(xb + (size_t)r1 * Hh + c8);
        accbf(A0, v0);
        accbf(A1, v1);
    }

    float i0 = 1.f / fmaxf((float)n0, 1.f);
    float i1 = 1.f / fmaxf((float)n1, 1.f);
    uint4 o0, o1;
    o0.x = pk2(A0[0].x * i0, A0[0].y * i0);
    o0.y = pk2(A0[1].x * i0, A0[1].y * i0);
    o0.z = pk2(A0[2].x * i0, A0[2].y * i0);
    o0.w = pk2(A0[3].x * i0, A0[3].y * i0);
    o1.x = pk2(A1[0].x * i1, A1[0].y * i1);
    o1.y = pk2(A1[1].x * i1, A1[1].y * i1);
    o1.z = pk2(A1[2].x * i1, A1[2].y * i1);
    o1.w = pk2(A1[3].x * i1, A1[3].y * i1);
    *(uint4*)(xg0 + (size_t)d * (Hh / 2) + gl * 4) = o0;
    *(uint4*)(xg1 + (size_t)d * (Hh / 2) + gl * 4) = o1;
}

// ---- fused GEMM: out = relu(xb@root + xg0@W0 + xg1@W1 + b), bf16 out.
//      512 thr / 256 rows per block; mat-outer loop staging one 32KB weight
//      matrix in LDS per iteration; fully-unrolled static acc[2][8]. ----
__global__ __launch_bounds__(512, 2) void gemm_fused(const unsigned short* __restrict__ x0,
                                                     const unsigned short* __restrict__ xg0,
                                                     const unsigned short* __restrict__ xg1,
                                                     const unsigned short* __restrict__ wl,
                                                     const float* __restrict__ bias,
                                                     unsigned short* __restrict__ out) {
    __shared__ unsigned short wlds[16384];   // one 128x128 bf16 weight matrix
    int t = threadIdx.x;
    int w = t >> 6, lane = t & 63;
    int m = lane & 15, ksel = lane >> 4;
    int row0 = blockIdx.x * 256 + w * 32;

    const unsigned short* srcs[3] = {x0, xg0, xg1};
    f32x4 acc[2][8];
    #pragma unroll
    for (int rt = 0; rt < 2; ++rt)
        #pragma unroll
        for (int cb = 0; cb < 8; ++cb) acc[rt][cb] = (f32x4){0.f, 0.f, 0.f, 0.f};

    #pragma unroll
    for (int mat = 0; mat < 3; ++mat) {
        if (mat) __syncthreads();
        {
            const uint4* ws_ = (const uint4*)(wl + (size_t)mat * 16384);
            uint4* wd_ = (uint4*)wlds;
            #pragma unroll
            for (int c = 0; c < 4; ++c) wd_[c * 512 + t] = ws_[c * 512 + t];
        }
        bf16x8 a[2][4];
        #pragma unroll
        for (int rt = 0; rt < 2; ++rt) {
            int node = row0 + rt * 16 + m;
            const unsigned short* xr = srcs[mat] + (size_t)node * Ff;
            #pragma unroll
            for (int s = 0; s < 4; ++s) {
                if (node < Nn) {
                    a[rt][s] = *(const bf16x8*)(xr + s * 32 + ksel * 8);
                } else {
                    #pragma unroll
                    for (int q = 0; q < 8; ++q) a[rt][s][q] = 0;
                }
            }
        }
        __syncthreads();
        #pragma unroll
        for (int cb = 0; cb < 8; ++cb) {
            #pragma unroll
            for (int s = 0; s < 4; ++s) {
                bf16x8 bfr = *(const bf16x8*)(wlds + (size_t)(cb * 4 + s) * 512 + lane * 8);
                acc[0][cb] = __builtin_amdgcn_mfma_f32_16x16x32_bf16(a[0][s], bfr, acc[0][cb], 0, 0, 0);
                acc[1][cb] = __builtin_amdgcn_mfma_f32_16x16x32_bf16(a[1][s], bfr, acc[1][cb], 0, 0, 0);
            }
        }
    }

    bool ev = (lane & 1) == 0;
    int j0 = ev ? 0 : 2;

    #pragma unroll
    for (int cb = 0; cb < 8; ++cb) {
        int col = cb * 16 + m;
        float bv = bias[col];
        int colb = col & ~1;
        #pragma unroll
        for (int rt = 0; rt < 2; ++rt) {
            f32x4 ac = acc[rt][cb];
            float o[4], po[4];
            #pragma unroll
            for (int j = 0; j < 4; ++j) o[j] = fmaxf(ac[j] + bv, 0.f);
            #pragma unroll
            for (int j = 0; j < 4; ++j) po[j] = __shfl_xor(o[j], 1);
            unsigned pkw0 = ev ? ((unsigned)f2bf(o[j0])      | ((unsigned)f2bf(po[j0])      << 16))
                               : ((unsigned)f2bf(po[j0])     | ((unsigned)f2bf(o[j0])       << 16));
            unsigned pkw1 = ev ? ((unsigned)f2bf(o[j0 + 1])  | ((unsigned)f2bf(po[j0 + 1])  << 16))
                               : ((unsigned)f2bf(po[j0 + 1]) | ((unsigned)f2bf(o[j0 + 1])   << 16));
            int rbase = row0 + rt * 16 + ksel * 4;
            int rr0 = rbase + j0, rr1 = rbase + j0 + 1;
            if (rr0 < Nn) *(unsigned*)(out + (size_t)rr0 * Hh + colb) = pkw0;
            if (rr1 < Nn) *(unsigned*)(out + (size_t)rr1 * Hh + colb) = pkw1;
        }
    }
}

// ---- pool + linear: one 8-wave block per graph ----
__global__ __launch_bounds__(512) void pool_linear(const unsigned int* __restrict__ xb,
                                                   const int* __restrict__ gstart,
                                                   const float* __restrict__ lin_w,
                                                   const float* __restrict__ lin_b,
                                                   float* __restrict__ out) {
    __shared__ float red[8][128];
    int g = blockIdx.x;
    int t = threadIdx.x;
    int w = t >> 6, lane = t & 63;
    int s = gstart[g], e = gstart[g + 1];

    float a0 = 0.f, a1 = 0.f;
    for (int n = s + w; n < e; n += 8) {
        unsigned u = xb[(size_t)n * (Hh / 2) + lane];
        a0 += __uint_as_float(u << 16);
        a1 += __uint_as_float(u & 0xffff0000u);
    }
    red[w][lane * 2]     = a0;
    red[w][lane * 2 + 1] = a1;
    __syncthreads();

    if (w == 0) {
        #pragma unroll
        for (int ww = 1; ww < 8; ++ww) {
            a0 += red[ww][lane * 2];
            a1 += red[ww][lane * 2 + 1];
        }
        float inv = 1.f / fmaxf((float)(e - s), 1.f);
        a0 *= inv; a1 *= inv;
        float p[Cc];
        int k0 = 2 * lane, k1 = 2 * lane + 1;
        #pragma unroll
        for (int c = 0; c < Cc; ++c)
            p[c] = a0 * lin_w[k0 * Cc + c] + a1 * lin_w[k1 * Cc + c];
        #pragma unroll
        for (int off = 32; off > 0; off >>= 1)
            #pragma unroll
            for (int c = 0; c < Cc; ++c)
                p[c] += __shfl_down(p[c], off, 64);
        if (lane == 0)
            #pragma unroll
            for (int c = 0; c < Cc; ++c) out[g * Cc + c] = p[c] + lin_b[c];
    }
}

static inline size_t alignup(size_t v) { return (v + 255) & ~(size_t)255; }

extern "C" void kernel_launch(void* const* d_in, const int* in_sizes, int n_in,
                              void* d_out, int out_size, void* d_ws, size_t ws_size,
                              hipStream_t stream) {
    const float* x     = (const float*)d_in[0];
    const int*   ei    = (const int*)d_in[1];
    const int*   ea    = (const int*)d_in[2];
    const int*   batch = (const int*)d_in[3];
    const float* W1 = (const float*)d_in[4];
    const float* r1 = (const float*)d_in[5];
    const float* b1 = (const float*)d_in[6];
    const float* W2 = (const float*)d_in[7];
    const float* r2 = (const float*)d_in[8];
    const float* b2 = (const float*)d_in[9];
    const float* W3 = (const float*)d_in[10];
    const float* r3 = (const float*)d_in[11];
    const float* b3 = (const float*)d_in[12];
    const float* lin_w = (const float*)d_in[13];
    const float* lin_b = (const float*)d_in[14];
    float* out = (float*)d_out;

    char* p = (char*)d_ws;
    unsigned short* xbA = (unsigned short*)p;  p += alignup((size_t)(Nn + 1) * Hh * 2);
    unsigned short* xbB = (unsigned short*)p;  p += alignup((size_t)(Nn + 1) * Hh * 2);
    unsigned short* xg0 = (unsigned short*)p;  p += alignup((size_t)Nn * Hh * 2);
    unsigned short* xg1 = (unsigned short*)p;  p += alignup((size_t)Nn * Hh * 2);
    unsigned short* wp  = (unsigned short*)p;  p += alignup((size_t)9 * 16384 * 2);
    int* rowstart    = (int*)p;                p += alignup((size_t)Nn * 4);
    int* mid         = (int*)p;                p += alignup((size_t)Nn * 4);
    int* cnts        = (int*)p;                p += alignup((size_t)Nn * 4);
    int* csr         = (int*)p;                p += alignup((size_t)NBK * BMAX * 4);
    int* bucketCur   = (int*)p;                p += alignup((size_t)NBK * 4);
    int* gstart      = (int*)p;                p += alignup((size_t)(Gg + 1) * 4);

    hipMemsetAsync(bucketCur, 0, (size_t)NBK * 4, stream);
    hipMemsetAsync(xbA + (size_t)Nn * Hh, 0, Hh * 2, stream);   // zero row at sentinel index Nn
    hipMemsetAsync(xbB + (size_t)Nn * Hh, 0, Hh * 2, stream);

    prep<<<CAST_BLKS + PACK_BLKS + GS_BLKS, 256, 0, stream>>>(
        x, (uint2*)xbA, W1, r1, W2, r2, W3, r3, wp, batch, gstart);

    bin_edges<<<NABLK, 512, 0, stream>>>(ei, ea, bucketCur, csr);
    sort_bucket<<<NBK, 512, 0, stream>>>(bucketCur, csr, rowstart, mid, cnts);

    int agg_grid = (Nn + 15) / 16;
    int gemm_grid = (Nn + 255) / 256;

    // layer 1: xbA -> xbB
    aggregate<<<agg_grid, 256, 0, stream>>>(xbA, csr, rowstart, mid, cnts, (unsigned int*)xg0, (unsigned int*)xg1);
    gemm_fused<<<gemm_grid, 512, 0, stream>>>(xbA, xg0, xg1, wp + 0 * 3 * 16384, b1, xbB);
    // layer 2: xbB -> xbA
    aggregate<<<agg_grid, 256, 0, stream>>>(xbB, csr, rowstart, mid, cnts, (unsigned int*)xg0, (unsigned int*)xg1);
    gemm_fused<<<gemm_grid, 512, 0, stream>>>(xbB, xg0, xg1, wp + 1 * 3 * 16384, b2, xbA);
    // layer 3: xbA -> xbB
    aggregate<<<agg_grid, 256, 0, stream>>>(xbA, csr, rowstart, mid, cnts, (unsigned int*)xg0, (unsigned int*)xg1);
    gemm_fused<<<gemm_grid, 512, 0, stream>>>(xbA, xg0, xg1, wp + 2 * 3 * 16384, b3, xbB);

    pool_linear<<<Gg, 512, 0, stream>>>((const unsigned int*)xbB, gstart, lin_w, lin_b, out);
}

// Round 21
// 349.686 us; speedup vs baseline: 1.0582x; 1.0582x over previous
//
#include <hip/hip_runtime.h>
#include <hip/hip_bf16.h>

#define Nn 100000
#define Ee 1600000
#define Ff 128
#define Hh 128
#define Cc 10
#define Gg 512

#define NBK 391                         // ceil(Nn/256) buckets of 256 dst
#define ABLK 4096                       // edges per bin_edges block
#define NABLK ((Ee + ABLK - 1) / ABLK)  // 391
#define BMAX 6656                       // padded bucket capacity

// merged prep+bin kernel, 512 threads/block, partitioned by blockIdx:
#define CAST512 ((Nn * Ff / 4 + 511) / 512)          // 6250
#define PACK512 ((9 * 16384 + 511) / 512)            // 288
#define GS512   ((Nn + 1 + 511) / 512)               // 196

typedef short bf16x8 __attribute__((ext_vector_type(8)));
typedef float f32x4 __attribute__((ext_vector_type(4)));
typedef float f32x2 __attribute__((ext_vector_type(2)));

__device__ __forceinline__ unsigned short f2bf(float f) {
    unsigned u = __float_as_uint(f);
    u += 0x7fffu + ((u >> 16) & 1u);
    return (unsigned short)(u >> 16);
}
__device__ __forceinline__ unsigned pk2(float a, float b) {
    return (unsigned)f2bf(a) | ((unsigned)f2bf(b) << 16);
}

// ---- merged: bin_edges | cast_x | pack_w | graph_starts (independent work,
//      one dispatch so they overlap instead of serializing on the stream) ----
__global__ __launch_bounds__(512) void prep_bin(const int* __restrict__ ei,
                                                const int* __restrict__ ea,
                                                int* __restrict__ bucketCur,
                                                int* __restrict__ csr,
                                                const float* __restrict__ x,
                                                uint2* __restrict__ xb,
                                                const float* __restrict__ W1, const float* __restrict__ r1,
                                                const float* __restrict__ W2, const float* __restrict__ r2,
                                                const float* __restrict__ W3, const float* __restrict__ r3,
                                                unsigned short* __restrict__ wp,
                                                const int* __restrict__ batch,
                                                int* __restrict__ gstart) {
    __shared__ int lcnt[512];
    __shared__ int lstart[512];
    __shared__ int gbase[512];
    __shared__ int lcur[512];
    __shared__ int stage[ABLK];
    __shared__ unsigned short sbkt[ABLK];
    int b = blockIdx.x;
    int t = threadIdx.x;
    if (b < NABLK) {
        // ---- bin_edges: LDS-staged binning by dst>>8 into padded buckets ----
        int base = b * ABLK;
        int nhere = min(ABLK, Ee - base);
        lcnt[t] = 0;
        __syncthreads();
        for (int j = t; j < nhere; j += 512)
            atomicAdd(&lcnt[ei[Ee + base + j] >> 8], 1);
        __syncthreads();
        int v = lcnt[t];
        if (t < NBK) gbase[t] = (v > 0) ? atomicAdd(&bucketCur[t], v) : 0;
        int* pa = lcnt; int* pb = lstart;
        for (int off = 1; off < 512; off <<= 1) {
            int xsum = pa[t] + ((t >= off) ? pa[t - off] : 0);
            __syncthreads();
            pb[t] = xsum;
            __syncthreads();
            int* tmp = pa; pa = pb; pb = tmp;
        }
        int excl = pa[t] - v;
        __syncthreads();
        lstart[t] = excl;
        lcur[t] = excl;
        __syncthreads();
        for (int j = t; j < nhere; j += 512) {
            int e = base + j;
            int d = ei[Ee + e];
            int srcv = ei[e];
            int r = ea[e] & 1;
            int bkt = d >> 8;
            int lp = atomicAdd(&lcur[bkt], 1);
            stage[lp] = (srcv << 9) | ((d & 255) << 1) | r;
            sbkt[lp] = (unsigned short)bkt;
        }
        __syncthreads();
        for (int j = t; j < nhere; j += 512) {
            int bkt = sbkt[j];
            csr[(size_t)bkt * BMAX + gbase[bkt] + (j - lstart[bkt])] = stage[j];
        }
    } else if (b < NABLK + CAST512) {
        int i = (b - NABLK) * 512 + t;
        if (i >= Nn * Ff / 4) return;
        float4 v = ((const float4*)x)[i];
        uint2 o;
        o.x = pk2(v.x, v.y);
        o.y = pk2(v.z, v.w);
        xb[i] = o;
    } else if (b < NABLK + CAST512 + PACK512) {
        int tt = (b - NABLK - CAST512) * 512 + t;
        if (tt >= 9 * 16384) return;
        int i = tt & 7, l = (tt >> 3) & 63, s = (tt >> 9) & 3, c = (tt >> 11) & 7, m = tt >> 14;
        int k = s * 32 + ((l >> 4) << 3) + i;
        int n = (c << 4) + (l & 15);
        int q = m / 3, j = m % 3;
        const float* Ws[3] = {W1, W2, W3};
        const float* rs[3] = {r1, r2, r3};
        const float* src = (j == 0) ? rs[q] : (Ws[q] + (size_t)(j - 1) * Ff * Hh);
        wp[tt] = f2bf(src[k * Hh + n]);
    } else {
        int n = (b - NABLK - CAST512 - PACK512) * 512 + t;
        if (n > Nn) return;
        int bp = (n == 0) ? -1 : batch[n - 1];
        int bc = (n == Nn) ? Gg : batch[n];
        for (int g = bp + 1; g <= bc; ++g) gstart[g] = n;
    }
}

// ---- CSR build, pass 2: per-bucket counting sort by (dstLow, rel).
//      Both relation segments padded to Lp = 4*ceil(max(n0,n1)/4), sentinel
//      src = Nn (zero row). Emits rowstart/mid + packed counts. ----
__global__ __launch_bounds__(512) void sort_bucket(const int* __restrict__ bucketCur,
                                                   int* __restrict__ csr,
                                                   int* __restrict__ rowstart,
                                                   int* __restrict__ mid,
                                                   int* __restrict__ cnts) {
    __shared__ int cnt_[512];
    __shared__ int sa_[512];
    __shared__ int sb_[512];
    __shared__ int cur_[512];
    __shared__ int stage[BMAX];
    __shared__ int npad_s;
    int b = blockIdx.x;
    int t = threadIdx.x;
    int s = b * BMAX;
    int n = bucketCur[b];
    cnt_[t] = 0;
    __syncthreads();
    for (int j = t; j < n; j += 512)
        atomicAdd(&cnt_[csr[(size_t)s + j] & 511], 1);
    __syncthreads();
    int c_self = cnt_[t];
    int c_pair = cnt_[t ^ 1];
    int Lp = (max(c_self, c_pair) + 3) & ~3;
    int v = Lp;
    sa_[t] = v;
    __syncthreads();
    int* pa = sa_; int* pb = sb_;
    for (int off = 1; off < 512; off <<= 1) {
        int x = pa[t] + ((t >= off) ? pa[t - off] : 0);
        __syncthreads();
        pb[t] = x;
        __syncthreads();
        int* tmp = pa; pa = pb; pb = tmp;
    }
    int excl = pa[t] - v;
    if (t == 511) npad_s = excl + v;
    __syncthreads();
    sa_[t] = excl;
    cur_[t] = excl;
    __syncthreads();
    int npad = npad_s;
    if (t < 256) {
        int d = b * 256 + t;
        if (d < Nn) {
            rowstart[d] = s + sa_[2 * t];
            mid[d]      = s + sa_[2 * t + 1];
            cnts[d]     = cnt_[2 * t] | (cnt_[2 * t + 1] << 16);
        }
    }
    for (int j = t; j < npad; j += 512) stage[j] = Nn;
    __syncthreads();
    for (int j = t; j < n; j += 512) {
        int rec = csr[(size_t)s + j];
        int lp = atomicAdd(&cur_[rec & 511], 1);
        stage[lp] = rec >> 9;          // src index
    }
    __syncthreads();
    for (int j = t; j < npad; j += 512)
        csr[(size_t)s + j] = stage[j];
}

// ---- aggregation: bound-check-free padded dual-relation interleave, unroll 2.
//      R19 layout (63 µs floor): quad slots + shfl reduce. Five structural
//      variants (R10/R13/R16/R18/R20) converge here — gather-path bound. ----
__device__ __forceinline__ void accbf(f32x2 A[4], uint4 v) {
    A[0] += (f32x2){__uint_as_float(v.x << 16), __uint_as_float(v.x & 0xffff0000u)};
    A[1] += (f32x2){__uint_as_float(v.y << 16), __uint_as_float(v.y & 0xffff0000u)};
    A[2] += (f32x2){__uint_as_float(v.z << 16), __uint_as_float(v.z & 0xffff0000u)};
    A[3] += (f32x2){__uint_as_float(v.w << 16), __uint_as_float(v.w & 0xffff0000u)};
}

__global__ __launch_bounds__(256) void aggregate(const unsigned short* __restrict__ xb,
                                                 const int* __restrict__ csr,
                                                 const int* __restrict__ rowstart,
                                                 const int* __restrict__ mid,
                                                 const int* __restrict__ cnts,
                                                 unsigned int* __restrict__ xg0,
                                                 unsigned int* __restrict__ xg1) {
    int d = blockIdx.x * 4 + (threadIdx.x >> 6);
    if (d >= Nn) return;
    int lane = threadIdx.x & 63;
    int slot = lane >> 4;           // which edge of a quad (0..3)
    int c8 = (lane & 15) * 8;       // this lane's 8 bf16 columns
    int s = rowstart[d], md = mid[d];
    int nq = (md - s) >> 2;         // same for both segments by construction

    f32x2 A0[4], A1[4];
    #pragma unroll
    for (int j = 0; j < 4; ++j) { A0[j] = (f32x2){0.f, 0.f}; A1[j] = (f32x2){0.f, 0.f}; }

    const int* p0 = csr + s + slot;
    const int* p1 = csr + md + slot;

    #pragma unroll 2
    for (int q = 0; q < nq; ++q) {
        int r0 = p0[q * 4];
        int r1 = p1[q * 4];
        uint4 v0 = *(const uint4*)(xb + (size_t)r0 * Hh + c8);
        uint4 v1 = *(const uint4*)(xb + (size_t)r1 * Hh + c8);
        accbf(A0, v0);
        accbf(A1, v1);
    }

    #pragma unroll
    for (int j = 0; j < 4; ++j) {
        A0[j].x += __shfl_xor(A0[j].x, 16); A0[j].y += __shfl_xor(A0[j].y, 16);
        A0[j].x += __shfl_xor(A0[j].x, 32); A0[j].y += __shfl_xor(A0[j].y, 32);
        A1[j].x += __shfl_xor(A1[j].x, 16); A1[j].y += __shfl_xor(A1[j].y, 16);
        A1[j].x += __shfl_xor(A1[j].x, 32); A1[j].y += __shfl_xor(A1[j].y, 32);
    }

    if (slot == 0) {
        int cn = cnts[d];
        int n0 = cn & 0xffff, n1 = cn >> 16;
        float i0 = 1.f / fmaxf((float)n0, 1.f);
        float i1 = 1.f / fmaxf((float)n1, 1.f);
        uint4 o0, o1;
        o0.x = pk2(A0[0].x * i0, A0[0].y * i0);
        o0.y = pk2(A0[1].x * i0, A0[1].y * i0);
        o0.z = pk2(A0[2].x * i0, A0[2].y * i0);
        o0.w = pk2(A0[3].x * i0, A0[3].y * i0);
        o1.x = pk2(A1[0].x * i1, A1[0].y * i1);
        o1.y = pk2(A1[1].x * i1, A1[1].y * i1);
        o1.z = pk2(A1[2].x * i1, A1[2].y * i1);
        o1.w = pk2(A1[3].x * i1, A1[3].y * i1);
        *(uint4*)(xg0 + (size_t)d * (Hh / 2) + (lane & 15) * 4) = o0;
        *(uint4*)(xg1 + (size_t)d * (Hh / 2) + (lane & 15) * 4) = o1;
    }
}

// ---- fused GEMM: out = relu(xb@root + xg0@W0 + xg1@W1 + b), bf16 out.
//      512 thr / 256 rows per block; mat-outer loop staging one 32KB weight
//      matrix in LDS per iteration; fully-unrolled static acc[2][8]. ----
__global__ __launch_bounds__(512, 2) void gemm_fused(const unsigned short* __restrict__ x0,
                                                     const unsigned short* __restrict__ xg0,
                                                     const unsigned short* __restrict__ xg1,
                                                     const unsigned short* __restrict__ wl,
                                                     const float* __restrict__ bias,
                                                     unsigned short* __restrict__ out) {
    __shared__ unsigned short wlds[16384];   // one 128x128 bf16 weight matrix
    int t = threadIdx.x;
    int w = t >> 6, lane = t & 63;
    int m = lane & 15, ksel = lane >> 4;
    int row0 = blockIdx.x * 256 + w * 32;

    const unsigned short* srcs[3] = {x0, xg0, xg1};
    f32x4 acc[2][8];
    #pragma unroll
    for (int rt = 0; rt < 2; ++rt)
        #pragma unroll
        for (int cb = 0; cb < 8; ++cb) acc[rt][cb] = (f32x4){0.f, 0.f, 0.f, 0.f};

    #pragma unroll
    for (int mat = 0; mat < 3; ++mat) {
        if (mat) __syncthreads();
        {
            const uint4* ws_ = (const uint4*)(wl + (size_t)mat * 16384);
            uint4* wd_ = (uint4*)wlds;
            #pragma unroll
            for (int c = 0; c < 4; ++c) wd_[c * 512 + t] = ws_[c * 512 + t];
        }
        bf16x8 a[2][4];
        #pragma unroll
        for (int rt = 0; rt < 2; ++rt) {
            int node = row0 + rt * 16 + m;
            const unsigned short* xr = srcs[mat] + (size_t)node * Ff;
            #pragma unroll
            for (int s = 0; s < 4; ++s) {
                if (node < Nn) {
                    a[rt][s] = *(const bf16x8*)(xr + s * 32 + ksel * 8);
                } else {
                    #pragma unroll
                    for (int q = 0; q < 8; ++q) a[rt][s][q] = 0;
                }
            }
        }
        __syncthreads();
        #pragma unroll
        for (int cb = 0; cb < 8; ++cb) {
            #pragma unroll
            for (int s = 0; s < 4; ++s) {
                bf16x8 bfr = *(const bf16x8*)(wlds + (size_t)(cb * 4 + s) * 512 + lane * 8);
                acc[0][cb] = __builtin_amdgcn_mfma_f32_16x16x32_bf16(a[0][s], bfr, acc[0][cb], 0, 0, 0);
                acc[1][cb] = __builtin_amdgcn_mfma_f32_16x16x32_bf16(a[1][s], bfr, acc[1][cb], 0, 0, 0);
            }
        }
    }

    bool ev = (lane & 1) == 0;
    int j0 = ev ? 0 : 2;

    #pragma unroll
    for (int cb = 0; cb < 8; ++cb) {
        int col = cb * 16 + m;
        float bv = bias[col];
        int colb = col & ~1;
        #pragma unroll
        for (int rt = 0; rt < 2; ++rt) {
            f32x4 ac = acc[rt][cb];
            float o[4], po[4];
            #pragma unroll
            for (int j = 0; j < 4; ++j) o[j] = fmaxf(ac[j] + bv, 0.f);
            #pragma unroll
            for (int j = 0; j < 4; ++j) po[j] = __shfl_xor(o[j], 1);
            unsigned pkw0 = ev ? ((unsigned)f2bf(o[j0])      | ((unsigned)f2bf(po[j0])      << 16))
                               : ((unsigned)f2bf(po[j0])     | ((unsigned)f2bf(o[j0])       << 16));
            unsigned pkw1 = ev ? ((unsigned)f2bf(o[j0 + 1])  | ((unsigned)f2bf(po[j0 + 1])  << 16))
                               : ((unsigned)f2bf(po[j0 + 1]) | ((unsigned)f2bf(o[j0 + 1])   << 16));
            int rbase = row0 + rt * 16 + ksel * 4;
            int rr0 = rbase + j0, rr1 = rbase + j0 + 1;
            if (rr0 < Nn) *(unsigned*)(out + (size_t)rr0 * Hh + colb) = pkw0;
            if (rr1 < Nn) *(unsigned*)(out + (size_t)rr1 * Hh + colb) = pkw1;
        }
    }
}

// ---- pool + linear: one 8-wave block per graph ----
__global__ __launch_bounds__(512) void pool_linear(const unsigned int* __restrict__ xb,
                                                   const int* __restrict__ gstart,
                                                   const float* __restrict__ lin_w,
                                                   const float* __restrict__ lin_b,
                                                   float* __restrict__ out) {
    __shared__ float red[8][128];
    int g = blockIdx.x;
    int t = threadIdx.x;
    int w = t >> 6, lane = t & 63;
    int s = gstart[g], e = gstart[g + 1];

    float a0 = 0.f, a1 = 0.f;
    for (int n = s + w; n < e; n += 8) {
        unsigned u = xb[(size_t)n * (Hh / 2) + lane];
        a0 += __uint_as_float(u << 16);
        a1 += __uint_as_float(u & 0xffff0000u);
    }
    red[w][lane * 2]     = a0;
    red[w][lane * 2 + 1] = a1;
    __syncthreads();

    if (w == 0) {
        #pragma unroll
        for (int ww = 1; ww < 8; ++ww) {
            a0 += red[ww][lane * 2];
            a1 += red[ww][lane * 2 + 1];
        }
        float inv = 1.f / fmaxf((float)(e - s), 1.f);
        a0 *= inv; a1 *= inv;
        float p[Cc];
        int k0 = 2 * lane, k1 = 2 * lane + 1;
        #pragma unroll
        for (int c = 0; c < Cc; ++c)
            p[c] = a0 * lin_w[k0 * Cc + c] + a1 * lin_w[k1 * Cc + c];
        #pragma unroll
        for (int off = 32; off > 0; off >>= 1)
            #pragma unroll
            for (int c = 0; c < Cc; ++c)
                p[c] += __shfl_down(p[c], off, 64);
        if (lane == 0)
            #pragma unroll
            for (int c = 0; c < Cc; ++c) out[g * Cc + c] = p[c] + lin_b[c];
    }
}

static inline size_t alignup(size_t v) { return (v + 255) & ~(size_t)255; }

extern "C" void kernel_launch(void* const* d_in, const int* in_sizes, int n_in,
                              void* d_out, int out_size, void* d_ws, size_t ws_size,
                              hipStream_t stream) {
    const float* x     = (const float*)d_in[0];
    const int*   ei    = (const int*)d_in[1];
    const int*   ea    = (const int*)d_in[2];
    const int*   batch = (const int*)d_in[3];
    const float* W1 = (const float*)d_in[4];
    const float* r1 = (const float*)d_in[5];
    const float* b1 = (const float*)d_in[6];
    const float* W2 = (const float*)d_in[7];
    const float* r2 = (const float*)d_in[8];
    const float* b2 = (const float*)d_in[9];
    const float* W3 = (const float*)d_in[10];
    const float* r3 = (const float*)d_in[11];
    const float* b3 = (const float*)d_in[12];
    const float* lin_w = (const float*)d_in[13];
    const float* lin_b = (const float*)d_in[14];
    float* out = (float*)d_out;

    char* p = (char*)d_ws;
    unsigned short* xbA = (unsigned short*)p;  p += alignup((size_t)(Nn + 1) * Hh * 2);
    unsigned short* xbB = (unsigned short*)p;  p += alignup((size_t)(Nn + 1) * Hh * 2);
    unsigned short* xg0 = (unsigned short*)p;  p += alignup((size_t)Nn * Hh * 2);
    unsigned short* xg1 = (unsigned short*)p;  p += alignup((size_t)Nn * Hh * 2);
    unsigned short* wp  = (unsigned short*)p;  p += alignup((size_t)9 * 16384 * 2);
    int* rowstart    = (int*)p;                p += alignup((size_t)Nn * 4);
    int* mid         = (int*)p;                p += alignup((size_t)Nn * 4);
    int* cnts        = (int*)p;                p += alignup((size_t)Nn * 4);
    int* csr         = (int*)p;                p += alignup((size_t)NBK * BMAX * 4);
    int* bucketCur   = (int*)p;                p += alignup((size_t)NBK * 4);
    int* gstart      = (int*)p;                p += alignup((size_t)(Gg + 1) * 4);

    hipMemsetAsync(bucketCur, 0, (size_t)NBK * 4, stream);
    hipMemsetAsync(xbA + (size_t)Nn * Hh, 0, Hh * 2, stream);   // zero row at sentinel index Nn
    hipMemsetAsync(xbB + (size_t)Nn * Hh, 0, Hh * 2, stream);

    prep_bin<<<NABLK + CAST512 + PACK512 + GS512, 512, 0, stream>>>(
        ei, ea, bucketCur, csr,
        x, (uint2*)xbA, W1, r1, W2, r2, W3, r3, wp, batch, gstart);

    sort_bucket<<<NBK, 512, 0, stream>>>(bucketCur, csr, rowstart, mid, cnts);

    int agg_grid = (Nn + 3) / 4;
    int gemm_grid = (Nn + 255) / 256;

    // layer 1: xbA -> xbB
    aggregate<<<agg_grid, 256, 0, stream>>>(xbA, csr, rowstart, mid, cnts, (unsigned int*)xg0, (unsigned int*)xg1);
    gemm_fused<<<gemm_grid, 512, 0, stream>>>(xbA, xg0, xg1, wp + 0 * 3 * 16384, b1, xbB);
    // layer 2: xbB -> xbA
    aggregate<<<agg_grid, 256, 0, stream>>>(xbB, csr, rowstart, mid, cnts, (unsigned int*)xg0, (unsigned int*)xg1);
    gemm_fused<<<gemm_grid, 512, 0, stream>>>(xbB, xg0, xg1, wp + 1 * 3 * 16384, b2, xbA);
    // layer 3: xbA -> xbB
    aggregate<<<agg_grid, 256, 0, stream>>>(xbA, csr, rowstart, mid, cnts, (unsigned int*)xg0, (unsigned int*)xg1);
    gemm_fused<<<gemm_grid, 512, 0, stream>>>(xbA, xg0, xg1, wp + 2 * 3 * 16384, b3, xbB);

    pool_linear<<<Gg, 512, 0, stream>>>((const unsigned int*)xbB, gstart, lin_w, lin_b, out);
}